// Round 4
// baseline (569.430 us; speedup 1.0000x reference)
//
#include <hip/hip_runtime.h>
#include <math.h>

#define NFFT   1024
#define HOPS   256
#define WINL   1024
#define PADL   384
#define BATCH  16
#define NFRAMES 2048
#define SPEC_K 513
#define SPEC_T 2048
#define OUT_PER_B  524288   // (NFRAMES-1)*HOP + WIN - 2*PAD
#define FULL_PER_B 525056   // (NFRAMES-1)*HOP + WIN

#define COLS 8       // frames per block (1 per wave)
#define STRIDEF 4    // finalize stride (t0 = 4j keeps float4 staging 16B-aligned)
#define JBLK 512     // blocks per batch
#define REGION 1044  // floats per col region (re[0..512], im[528..1040], time[0..1023])
#define SIMOFF 528   // imag plane offset: 16-bank shift vs re plane -> phase-1 stores 2-way free

struct C2 { float x, y; };

__device__ __forceinline__ C2 cadd(C2 a, C2 b){ return {a.x+b.x, a.y+b.y}; }
__device__ __forceinline__ C2 csub(C2 a, C2 b){ return {a.x-b.x, a.y-b.y}; }
__device__ __forceinline__ C2 cmul(C2 a, C2 b){ return {a.x*b.x - a.y*b.y, a.x*b.y + a.y*b.x}; }
__device__ __forceinline__ C2 muli(C2 a){ return {-a.y, a.x}; }

// 8-point inverse DFT (no scale)
__device__ __forceinline__ void idft8(C2* v) {
    C2 e0=v[0], e1=v[2], e2=v[4], e3=v[6];
    C2 o0=v[1], o1=v[3], o2=v[5], o3=v[7];
    C2 a0=cadd(e0,e2), a1=csub(e0,e2), a2=cadd(e1,e3), a3=csub(e1,e3);
    C2 E0=cadd(a0,a2), E1=cadd(a1,muli(a3)), E2=csub(a0,a2), E3=csub(a1,muli(a3));
    C2 b0=cadd(o0,o2), b1=csub(o0,o2), b2=cadd(o1,o3), b3=csub(o1,o3);
    C2 O0=cadd(b0,b2), O1=cadd(b1,muli(b3)), O2=csub(b0,b2), O3=csub(b1,muli(b3));
    const float s = 0.7071067811865476f;
    C2 t1 = {  s*(O1.x - O1.y), s*(O1.x + O1.y) };
    C2 t2 = muli(O2);
    C2 t3 = { -s*(O3.x + O3.y), s*(O3.x - O3.y) };
    v[0]=cadd(E0,O0); v[4]=csub(E0,O0);
    v[1]=cadd(E1,t1); v[5]=csub(E1,t1);
    v[2]=cadd(E2,t2); v[6]=csub(E2,t2);
    v[3]=cadd(E3,t3); v[7]=csub(E3,t3);
}

// distributed 8x8 transpose between the 3-bit lane field at bit S and the reg index
template<int S>
__device__ __forceinline__ void xpose(C2* v, int lane) {
    #pragma unroll
    for (int b = 0; b < 3; ++b) {
        const int rb = 1 << b, s = 1 << (S + b);
        int myb = (lane >> (S + b)) & 1;
        #pragma unroll
        for (int r0 = 0; r0 < 8; ++r0) {
            if (r0 & rb) continue;
            const int r1 = r0 | rb;
            float sx = myb ? v[r0].x : v[r1].x;
            float sy = myb ? v[r0].y : v[r1].y;
            float rx = __shfl_xor(sx, s, 64);
            float ry = __shfl_xor(sy, s, 64);
            if (myb) { v[r0].x = rx; v[r0].y = ry; }
            else     { v[r1].x = rx; v[r1].y = ry; }
        }
    }
}

__global__ __launch_bounds__(512, 8)
void istft_kernel(const float* __restrict__ sr, const float* __restrict__ si,
                  const float* __restrict__ win, float* __restrict__ out)
{
    __shared__ float lds[COLS*REGION];   // per-col: spec planes -> windowed time frame
    __shared__ float swin[WINL];

    int h  = blockIdx.x;
    int L  = (h & 7) * (BATCH*JBLK/8) + (h >> 3);   // XCD-aware swizzle
    int b  = L >> 9;          // / JBLK
    int j  = L & (JBLK-1);
    int t0 = j * STRIDEF;
    int tid = threadIdx.x;
    int lane = tid & 63, wave = tid >> 6;

    for (int i = tid; i < WINL; i += 512) swin[i] = win[i];

    // ---- phase 1: vectorized global -> LDS spec copy (16B-aligned: t0 % 4 == 0) ----
    const float* srb = sr + (size_t)b * SPEC_K * SPEC_T;
    const float* sib = si + (size_t)b * SPEC_K * SPEC_T;
    for (int c = tid; c < SPEC_K*4; c += 512) {       // 513 k x {re,im} x {u=0,1}
        int k = c >> 2, sub = c & 3;
        int arr = sub >> 1, u = sub & 1;
        const float* src = arr ? sib : srb;
        int tbase = t0 + 4*u;
        float4 val;
        if (tbase + 4 <= NFRAMES) {
            val = *(const float4*)&src[(size_t)k*SPEC_T + tbase];
        } else {
            float tmp[4];
            #pragma unroll
            for (int i = 0; i < 4; ++i) {
                int t = tbase + i;
                tmp[i] = (t < NFRAMES) ? src[(size_t)k*SPEC_T + t] : 0.f;
            }
            val = {tmp[0], tmp[1], tmp[2], tmp[3]};
        }
        int off = arr ? SIMOFF : 0;
        lds[(4*u+0)*REGION + off + k] = val.x;
        lds[(4*u+1)*REGION + off + k] = val.y;
        lds[(4*u+2)*REGION + off + k] = val.z;
        lds[(4*u+3)*REGION + off + k] = val.w;
    }
    __syncthreads();

    // ---- phase 2: one 512-pt inverse FFT per wave; cross-lane via shfl only ----
    if (t0 + wave < NFRAMES) {
        float* reg = &lds[wave*REGION];
        C2 v[8];

        // W-pack: W[k] = (E + i*rot*D)/512, rot = e^{2pi i k/1024}, k = lane + 64c
        float rr, ri;
        __sincosf((float)lane * 0.006135923151542565f, &ri, &rr);   // e^{2pi i lane/1024}
        const float stc = 0.92387953251128675613f;  // cos(2pi/16)  [step for k += 64]
        const float sts = 0.38268343236508977173f;  // sin(2pi/16)
        const float inv512 = 0.001953125f;
        #pragma unroll
        for (int c = 0; c < 8; ++c) {
            int k = lane + 64*c;
            float Ar = reg[k],       Ai = reg[SIMOFF + k];
            float Br = reg[512 - k], Bi = reg[SIMOFF + 512 - k];
            if (k == 0) { Ai = 0.f; Bi = 0.f; }     // bins 0/512: imag ignored
            float Er = 0.5f*(Ar+Br), Ei = 0.5f*(Ai-Bi);
            float Dr = 0.5f*(Ar-Br), Di = 0.5f*(Ai+Bi);
            float Or = rr*Dr - ri*Di, Oi = rr*Di + ri*Dr;
            v[c] = { (Er - Oi)*inv512, (Ei + Or)*inv512 };
            float nr = rr*stc - ri*sts; ri = rr*sts + ri*stc; rr = nr;   // rot *= e^{2pi i/16}
        }

        idft8(v);                 // stage 1
        xpose<3>(v, lane);

        C2 w2b; __sincosf((float)(lane>>3) * 0.09817477042468103f, &w2b.y, &w2b.x);
        C2 w = {1.f, 0.f};
        #pragma unroll
        for (int bb = 1; bb < 8; ++bb) { w = cmul(w, w2b); v[bb] = cmul(v[bb], w); }
        idft8(v);                 // stage 2
        xpose<0>(v, lane);

        int up = (lane>>3) + 8*(lane&7);
        C2 w3b; __sincosf((float)up * 0.012271846303085129f, &w3b.y, &w3b.x);
        w = {1.f, 0.f};
        #pragma unroll
        for (int aa = 1; aa < 8; ++aa) { w = cmul(w, w3b); v[aa] = cmul(v[aa], w); }
        idft8(v);                 // stage 3

        // unpack z[m] -> x[2m], x[2m+1]; window; overwrite own col region (contiguous)
        #pragma unroll
        for (int m2 = 0; m2 < 8; ++m2) {
            int n = 2*(up + 64*m2);
            float2 o = { v[m2].x * swin[n], v[m2].y * swin[n+1] };
            *(float2*)&reg[n] = o;
        }
    }
    __syncthreads();

    // ---- phase 3: finalize exclusive span (sum <=4 frames + envelope divide) ----
    int p_start = (j == 0) ? 0 : (t0 + COLS - STRIDEF) * HOPS;
    int p_end   = (t0 + COLS) * HOPS;
    if (p_end > FULL_PER_B) p_end = FULL_PER_B;
    float* outb = out + (size_t)b * OUT_PER_B;
    for (int p = p_start + tid; p < p_end; p += 512) {
        int o = p - PADL;
        if (o < 0 || o >= OUT_PER_B) continue;
        int thi = p >> 8;          if (thi > NFRAMES-1) thi = NFRAMES-1;
        int tlo = (p - 768) >> 8;  if (tlo < 0) tlo = 0;
        float sum = 0.f, env = 0.f;
        for (int t = tlo; t <= thi; ++t) {
            int n = p - (t << 8);
            float wv = swin[n];
            sum += lds[(t - t0)*REGION + n];
            env += wv * wv;
        }
        outb[o] = sum / fmaxf(env, 1e-11f);
    }
}

extern "C" void kernel_launch(void* const* d_in, const int* in_sizes, int n_in,
                              void* d_out, int out_size, void* d_ws, size_t ws_size,
                              hipStream_t stream) {
    const float* sr  = (const float*)d_in[0];
    const float* si  = (const float*)d_in[1];
    const float* win = (const float*)d_in[2];
    float* out = (float*)d_out;
    istft_kernel<<<dim3(BATCH*JBLK), dim3(512), 0, stream>>>(sr, si, win, out);
}

// Round 5
// 568.683 us; speedup vs baseline: 1.0013x; 1.0013x over previous
//
#include <hip/hip_runtime.h>
#include <math.h>

#define NFFT   1024
#define HOPS   256
#define WINL   1024
#define PADL   384
#define BATCH  16
#define NFRAMES 2048
#define SPEC_K 513
#define SPEC_T 2048
#define OUT_PER_B  524288   // (NFRAMES-1)*HOP + WIN - 2*PAD
#define FULL_PER_B 525056   // (NFRAMES-1)*HOP + WIN

#define COLS 8       // frames per block (1 per wave)
#define STRIDEF 4    // finalize stride (t0 = 4j keeps float4 staging 16B-aligned)
#define JBLK 512     // blocks per batch
#define REGION 1044  // floats per col region (re[0..512], im[528..1040], time[0..1023])
#define SIMOFF 528   // imag plane offset: 16-bank shift vs re plane -> phase-1 stores 2-way free

struct C2 { float x, y; };

__device__ __forceinline__ C2 cadd(C2 a, C2 b){ return {a.x+b.x, a.y+b.y}; }
__device__ __forceinline__ C2 csub(C2 a, C2 b){ return {a.x-b.x, a.y-b.y}; }
__device__ __forceinline__ C2 cmul(C2 a, C2 b){ return {a.x*b.x - a.y*b.y, a.x*b.y + a.y*b.x}; }
__device__ __forceinline__ C2 muli(C2 a){ return {-a.y, a.x}; }

// 8-point inverse DFT (no scale)
__device__ __forceinline__ void idft8(C2* v) {
    C2 e0=v[0], e1=v[2], e2=v[4], e3=v[6];
    C2 o0=v[1], o1=v[3], o2=v[5], o3=v[7];
    C2 a0=cadd(e0,e2), a1=csub(e0,e2), a2=cadd(e1,e3), a3=csub(e1,e3);
    C2 E0=cadd(a0,a2), E1=cadd(a1,muli(a3)), E2=csub(a0,a2), E3=csub(a1,muli(a3));
    C2 b0=cadd(o0,o2), b1=csub(o0,o2), b2=cadd(o1,o3), b3=csub(o1,o3);
    C2 O0=cadd(b0,b2), O1=cadd(b1,muli(b3)), O2=csub(b0,b2), O3=csub(b1,muli(b3));
    const float s = 0.7071067811865476f;
    C2 t1 = {  s*(O1.x - O1.y), s*(O1.x + O1.y) };
    C2 t2 = muli(O2);
    C2 t3 = { -s*(O3.x + O3.y), s*(O3.x - O3.y) };
    v[0]=cadd(E0,O0); v[4]=csub(E0,O0);
    v[1]=cadd(E1,t1); v[5]=csub(E1,t1);
    v[2]=cadd(E2,t2); v[6]=csub(E2,t2);
    v[3]=cadd(E3,t3); v[7]=csub(E3,t3);
}

// distributed 8x8 transpose between the 3-bit lane field at bit S and the reg index
template<int S>
__device__ __forceinline__ void xpose(C2* v, int lane) {
    #pragma unroll
    for (int b = 0; b < 3; ++b) {
        const int rb = 1 << b, s = 1 << (S + b);
        int myb = (lane >> (S + b)) & 1;
        #pragma unroll
        for (int r0 = 0; r0 < 8; ++r0) {
            if (r0 & rb) continue;
            const int r1 = r0 | rb;
            float sx = myb ? v[r0].x : v[r1].x;
            float sy = myb ? v[r0].y : v[r1].y;
            float rx = __shfl_xor(sx, s, 64);
            float ry = __shfl_xor(sy, s, 64);
            if (myb) { v[r0].x = rx; v[r0].y = ry; }
            else     { v[r1].x = rx; v[r1].y = ry; }
        }
    }
}

// launch_bounds(512,4): VGPR cap 128. (512,8) forced a 64-VGPR cap -> compiler
// spilled the whole FFT to scratch (R4: VGPR=32, WRITE_SIZE 650MB, 475us).
__global__ __launch_bounds__(512, 4)
void istft_kernel(const float* __restrict__ sr, const float* __restrict__ si,
                  const float* __restrict__ win, float* __restrict__ out)
{
    __shared__ float lds[COLS*REGION];   // per-col: spec planes -> windowed time frame
    __shared__ float swin[WINL];

    int h  = blockIdx.x;
    int L  = (h & 7) * (BATCH*JBLK/8) + (h >> 3);   // XCD-aware swizzle
    int b  = L >> 9;          // / JBLK
    int j  = L & (JBLK-1);
    int t0 = j * STRIDEF;
    int tid = threadIdx.x;
    int lane = tid & 63, wave = tid >> 6;

    for (int i = tid; i < WINL; i += 512) swin[i] = win[i];

    // ---- phase 1: vectorized global -> LDS spec copy (16B-aligned: t0 % 4 == 0) ----
    const float* srb = sr + (size_t)b * SPEC_K * SPEC_T;
    const float* sib = si + (size_t)b * SPEC_K * SPEC_T;
    for (int c = tid; c < SPEC_K*4; c += 512) {       // 513 k x {re,im} x {u=0,1}
        int k = c >> 2, sub = c & 3;
        int arr = sub >> 1, u = sub & 1;
        const float* src = arr ? sib : srb;
        int tbase = t0 + 4*u;
        float4 val;
        if (tbase + 4 <= NFRAMES) {
            val = *(const float4*)&src[(size_t)k*SPEC_T + tbase];
        } else {
            float tmp[4];
            #pragma unroll
            for (int i = 0; i < 4; ++i) {
                int t = tbase + i;
                tmp[i] = (t < NFRAMES) ? src[(size_t)k*SPEC_T + t] : 0.f;
            }
            val = {tmp[0], tmp[1], tmp[2], tmp[3]};
        }
        int off = arr ? SIMOFF : 0;
        lds[(4*u+0)*REGION + off + k] = val.x;
        lds[(4*u+1)*REGION + off + k] = val.y;
        lds[(4*u+2)*REGION + off + k] = val.z;
        lds[(4*u+3)*REGION + off + k] = val.w;
    }
    __syncthreads();

    // ---- phase 2: one 512-pt inverse FFT per wave; cross-lane via shfl only ----
    if (t0 + wave < NFRAMES) {
        float* reg = &lds[wave*REGION];
        C2 v[8];

        // W-pack: W[k] = (E + i*rot*D)/512, rot = e^{2pi i k/1024}, k = lane + 64c
        float rr, ri;
        __sincosf((float)lane * 0.006135923151542565f, &ri, &rr);   // e^{2pi i lane/1024}
        const float stc = 0.92387953251128675613f;  // cos(2pi/16)  [step for k += 64]
        const float sts = 0.38268343236508977173f;  // sin(2pi/16)
        const float inv512 = 0.001953125f;
        #pragma unroll
        for (int c = 0; c < 8; ++c) {
            int k = lane + 64*c;
            float Ar = reg[k],       Ai = reg[SIMOFF + k];
            float Br = reg[512 - k], Bi = reg[SIMOFF + 512 - k];
            if (k == 0) { Ai = 0.f; Bi = 0.f; }     // bins 0/512: imag ignored
            float Er = 0.5f*(Ar+Br), Ei = 0.5f*(Ai-Bi);
            float Dr = 0.5f*(Ar-Br), Di = 0.5f*(Ai+Bi);
            float Or = rr*Dr - ri*Di, Oi = rr*Di + ri*Dr;
            v[c] = { (Er - Oi)*inv512, (Ei + Or)*inv512 };
            float nr = rr*stc - ri*sts; ri = rr*sts + ri*stc; rr = nr;   // rot *= e^{2pi i/16}
        }

        idft8(v);                 // stage 1
        xpose<3>(v, lane);

        C2 w2b; __sincosf((float)(lane>>3) * 0.09817477042468103f, &w2b.y, &w2b.x);
        C2 w = {1.f, 0.f};
        #pragma unroll
        for (int bb = 1; bb < 8; ++bb) { w = cmul(w, w2b); v[bb] = cmul(v[bb], w); }
        idft8(v);                 // stage 2
        xpose<0>(v, lane);

        int up = (lane>>3) + 8*(lane&7);
        C2 w3b; __sincosf((float)up * 0.012271846303085129f, &w3b.y, &w3b.x);
        w = {1.f, 0.f};
        #pragma unroll
        for (int aa = 1; aa < 8; ++aa) { w = cmul(w, w3b); v[aa] = cmul(v[aa], w); }
        idft8(v);                 // stage 3

        // unpack z[m] -> x[2m], x[2m+1]; window; overwrite own col region (contiguous)
        #pragma unroll
        for (int m2 = 0; m2 < 8; ++m2) {
            int n = 2*(up + 64*m2);
            float2 o = { v[m2].x * swin[n], v[m2].y * swin[n+1] };
            *(float2*)&reg[n] = o;
        }
    }
    __syncthreads();

    // ---- phase 3: finalize exclusive span (sum <=4 frames + envelope divide) ----
    int p_start = (j == 0) ? 0 : (t0 + COLS - STRIDEF) * HOPS;
    int p_end   = (t0 + COLS) * HOPS;
    if (p_end > FULL_PER_B) p_end = FULL_PER_B;
    float* outb = out + (size_t)b * OUT_PER_B;
    for (int p = p_start + tid; p < p_end; p += 512) {
        int o = p - PADL;
        if (o < 0 || o >= OUT_PER_B) continue;
        int thi = p >> 8;          if (thi > NFRAMES-1) thi = NFRAMES-1;
        int tlo = (p - 768) >> 8;  if (tlo < 0) tlo = 0;
        float sum = 0.f, env = 0.f;
        for (int t = tlo; t <= thi; ++t) {
            int n = p - (t << 8);
            float wv = swin[n];
            sum += lds[(t - t0)*REGION + n];
            env += wv * wv;
        }
        outb[o] = sum / fmaxf(env, 1e-11f);
    }
}

extern "C" void kernel_launch(void* const* d_in, const int* in_sizes, int n_in,
                              void* d_out, int out_size, void* d_ws, size_t ws_size,
                              hipStream_t stream) {
    const float* sr  = (const float*)d_in[0];
    const float* si  = (const float*)d_in[1];
    const float* win = (const float*)d_in[2];
    float* out = (float*)d_out;
    istft_kernel<<<dim3(BATCH*JBLK), dim3(512), 0, stream>>>(sr, si, win, out);
}

// Round 6
// 249.870 us; speedup vs baseline: 2.2789x; 2.2759x over previous
//
#include <hip/hip_runtime.h>
#include <math.h>

#define NFFT   1024
#define HOPS   256
#define WINL   1024
#define PADL   384
#define BATCH  16
#define NFRAMES 2048
#define SPEC_K 513
#define SPEC_T 2048
#define OUT_PER_B  524288   // (NFRAMES-1)*HOP + WIN - 2*PAD
#define FULL_PER_B 525056   // (NFRAMES-1)*HOP + WIN

#define COLS 8       // frames per block (1 per wave)
#define STRIDEF 4    // finalize stride (t0 = 4j keeps float4 staging 16B-aligned)
#define JBLK 512     // blocks per batch
#define REGION 1044  // floats per col region (re[0..512], im[528..1040], time[0..1023])
#define SIMOFF 528   // imag plane offset (16-bank shift vs re plane)

struct C2 { float x, y; };

__device__ __forceinline__ C2 cadd(C2 a, C2 b){ return {a.x+b.x, a.y+b.y}; }
__device__ __forceinline__ C2 csub(C2 a, C2 b){ return {a.x-b.x, a.y-b.y}; }
__device__ __forceinline__ C2 cmul(C2 a, C2 b){ return {a.x*b.x - a.y*b.y, a.x*b.y + a.y*b.x}; }
__device__ __forceinline__ C2 muli(C2 a){ return {-a.y, a.x}; }

// 8-point inverse DFT on 8 named values (no arrays -> nothing to demote to scratch)
__device__ __forceinline__ void idft8r(C2&x0,C2&x1,C2&x2,C2&x3,C2&x4,C2&x5,C2&x6,C2&x7) {
    C2 e0=x0,e1=x2,e2=x4,e3=x6, o0=x1,o1=x3,o2=x5,o3=x7;
    C2 a0=cadd(e0,e2), a1=csub(e0,e2), a2=cadd(e1,e3), a3=csub(e1,e3);
    C2 E0=cadd(a0,a2), E1=cadd(a1,muli(a3)), E2=csub(a0,a2), E3=csub(a1,muli(a3));
    C2 b0=cadd(o0,o2), b1=csub(o0,o2), b2=cadd(o1,o3), b3=csub(o1,o3);
    C2 O0=cadd(b0,b2), O1=cadd(b1,muli(b3)), O2=csub(b0,b2), O3=csub(b1,muli(b3));
    const float s = 0.7071067811865476f;
    C2 t1 = {  s*(O1.x - O1.y), s*(O1.x + O1.y) };
    C2 t2 = muli(O2);
    C2 t3 = { -s*(O3.x + O3.y), s*(O3.x - O3.y) };
    x0=cadd(E0,O0); x4=csub(E0,O0);
    x1=cadd(E1,t1); x5=csub(E1,t1);
    x2=cadd(E2,t2); x6=csub(E2,t2);
    x3=cadd(E3,t3); x7=csub(E3,t3);
}

// exchange one reg-bit with one lane-bit: myb lane keeps partner's b-slot in a, etc.
template<int SH>
__device__ __forceinline__ void exch(C2& a, C2& b, int myb) {
    float sx = myb ? a.x : b.x;
    float sy = myb ? a.y : b.y;
    float rx = __shfl_xor(sx, SH, 64);
    float ry = __shfl_xor(sy, SH, 64);
    if (myb) { a.x = rx; a.y = ry; } else { b.x = rx; b.y = ry; }
}

__global__ __launch_bounds__(512, 4)
void istft_kernel(const float* __restrict__ sr, const float* __restrict__ si,
                  const float* __restrict__ win, float* __restrict__ out)
{
    __shared__ float lds[COLS*REGION];   // per-col: spec planes -> windowed time frame
    __shared__ float swin[WINL];

    int h  = blockIdx.x;
    int L  = (h & 7) * (BATCH*JBLK/8) + (h >> 3);   // XCD-aware swizzle
    int b  = L >> 9;          // / JBLK
    int j  = L & (JBLK-1);
    int t0 = j * STRIDEF;
    int tid = threadIdx.x;
    int lane = tid & 63, wave = tid >> 6;

    for (int i = tid; i < WINL; i += 512) swin[i] = win[i];

    // ---- phase 1: vectorized global -> LDS spec copy (16B-aligned: t0 % 4 == 0) ----
    const float* srb = sr + (size_t)b * SPEC_K * SPEC_T;
    const float* sib = si + (size_t)b * SPEC_K * SPEC_T;
    for (int c = tid; c < SPEC_K*4; c += 512) {       // 513 k x {re,im} x {u=0,1}
        int k = c >> 2, sub = c & 3;
        int arr = sub >> 1, u = sub & 1;
        const float* src = arr ? sib : srb;
        int tbase = t0 + 4*u;
        float4 val;
        if (tbase + 4 <= NFRAMES) {
            val = *(const float4*)&src[(size_t)k*SPEC_T + tbase];
        } else {
            float t0v = (tbase   < NFRAMES) ? src[(size_t)k*SPEC_T + tbase  ] : 0.f;
            float t1v = (tbase+1 < NFRAMES) ? src[(size_t)k*SPEC_T + tbase+1] : 0.f;
            float t2v = (tbase+2 < NFRAMES) ? src[(size_t)k*SPEC_T + tbase+2] : 0.f;
            float t3v = (tbase+3 < NFRAMES) ? src[(size_t)k*SPEC_T + tbase+3] : 0.f;
            val = {t0v, t1v, t2v, t3v};
        }
        int off = arr ? SIMOFF : 0;
        lds[(4*u+0)*REGION + off + k] = val.x;
        lds[(4*u+1)*REGION + off + k] = val.y;
        lds[(4*u+2)*REGION + off + k] = val.z;
        lds[(4*u+3)*REGION + off + k] = val.w;
    }
    __syncthreads();

    // ---- phase 2: one 512-pt inverse FFT per wave; straight-line, no guard
    //      (out-of-range frames were zero-staged; phase 3 never reads them) ----
    {
        float* reg = &lds[wave*REGION];
        C2 v0,v1,v2,v3,v4,v5,v6,v7;

        float rr, ri;
        __sincosf((float)lane * 0.006135923151542565f, &ri, &rr);   // e^{2pi i lane/1024}
        const float stc = 0.92387953251128675613f;  // cos(2pi/16)  [step for k += 64]
        const float sts = 0.38268343236508977173f;  // sin(2pi/16)
        const float inv512 = 0.001953125f;

        // W-pack: W[k] = (E + i*rot*D)/512, rot = e^{2pi i k/1024}, k = lane + 64*c
        #define PACK(c, vv) { \
            int k = lane + 64*(c); \
            float Ar = reg[k],       Ai = reg[SIMOFF + k]; \
            float Br = reg[512 - k], Bi = reg[SIMOFF + 512 - k]; \
            if (k == 0) { Ai = 0.f; Bi = 0.f; } \
            float Er = 0.5f*(Ar+Br), Ei = 0.5f*(Ai-Bi); \
            float Dr = 0.5f*(Ar-Br), Di = 0.5f*(Ai+Bi); \
            float Or = rr*Dr - ri*Di, Oi = rr*Di + ri*Dr; \
            vv = { (Er - Oi)*inv512, (Ei + Or)*inv512 }; \
            float nr = rr*stc - ri*sts; ri = rr*sts + ri*stc; rr = nr; }
        PACK(0,v0) PACK(1,v1) PACK(2,v2) PACK(3,v3)
        PACK(4,v4) PACK(5,v5) PACK(6,v6) PACK(7,v7)
        #undef PACK

        idft8r(v0,v1,v2,v3,v4,v5,v6,v7);          // stage 1 (over c -> m0)

        // transpose: reg bit0<->lane bit3, bit1<->bit4, bit2<->bit5
        {
            int b3 = (lane>>3)&1, b4 = (lane>>4)&1, b5 = (lane>>5)&1;
            exch<8> (v0,v1,b3); exch<8> (v2,v3,b3); exch<8> (v4,v5,b3); exch<8> (v6,v7,b3);
            exch<16>(v0,v2,b4); exch<16>(v1,v3,b4); exch<16>(v4,v6,b4); exch<16>(v5,v7,b4);
            exch<32>(v0,v4,b5); exch<32>(v1,v5,b5); exch<32>(v2,v6,b5); exch<32>(v3,v7,b5);
        }

        // stage-2 twiddles: e^{2pi i q*m02/64}, m02 = lane>>3
        {
            float cr, ci; __sincosf((float)(lane>>3) * 0.09817477042468103f, &ci, &cr);
            C2 wb = {cr, ci};
            C2 w = wb;
            v1 = cmul(v1, w);
            w = cmul(w, wb); v2 = cmul(v2, w);
            w = cmul(w, wb); v3 = cmul(v3, w);
            w = cmul(w, wb); v4 = cmul(v4, w);
            w = cmul(w, wb); v5 = cmul(v5, w);
            w = cmul(w, wb); v6 = cmul(v6, w);
            w = cmul(w, wb); v7 = cmul(v7, w);
        }
        idft8r(v0,v1,v2,v3,v4,v5,v6,v7);          // stage 2

        // transpose: reg bit0<->lane bit0, bit1<->bit1, bit2<->bit2
        {
            int b0 = lane&1, b1 = (lane>>1)&1, b2 = (lane>>2)&1;
            exch<1>(v0,v1,b0); exch<1>(v2,v3,b0); exch<1>(v4,v5,b0); exch<1>(v6,v7,b0);
            exch<2>(v0,v2,b1); exch<2>(v1,v3,b1); exch<2>(v4,v6,b1); exch<2>(v5,v7,b1);
            exch<4>(v0,v4,b2); exch<4>(v1,v5,b2); exch<4>(v2,v6,b2); exch<4>(v3,v7,b2);
        }

        // stage-3 twiddles: e^{2pi i q*up/512}, up = (lane>>3) + 8*(lane&7)
        int up = (lane>>3) + 8*(lane&7);
        {
            float cr, ci; __sincosf((float)up * 0.012271846303085129f, &ci, &cr);
            C2 wb = {cr, ci};
            C2 w = wb;
            v1 = cmul(v1, w);
            w = cmul(w, wb); v2 = cmul(v2, w);
            w = cmul(w, wb); v3 = cmul(v3, w);
            w = cmul(w, wb); v4 = cmul(v4, w);
            w = cmul(w, wb); v5 = cmul(v5, w);
            w = cmul(w, wb); v6 = cmul(v6, w);
            w = cmul(w, wb); v7 = cmul(v7, w);
        }
        idft8r(v0,v1,v2,v3,v4,v5,v6,v7);          // stage 3

        // unpack z[m] -> x[2m], x[2m+1]; window; overwrite own col region (contiguous)
        #define UNPK(m2, vv) { \
            int n = 2*(up + 64*(m2)); \
            float2 o = { vv.x * swin[n], vv.y * swin[n+1] }; \
            *(float2*)&reg[n] = o; }
        UNPK(0,v0) UNPK(1,v1) UNPK(2,v2) UNPK(3,v3)
        UNPK(4,v4) UNPK(5,v5) UNPK(6,v6) UNPK(7,v7)
        #undef UNPK
    }
    __syncthreads();

    // ---- phase 3: finalize exclusive span (sum <=4 frames + envelope divide) ----
    int p_start = (j == 0) ? 0 : (t0 + COLS - STRIDEF) * HOPS;
    int p_end   = (t0 + COLS) * HOPS;
    if (p_end > FULL_PER_B) p_end = FULL_PER_B;
    float* outb = out + (size_t)b * OUT_PER_B;
    for (int p = p_start + tid; p < p_end; p += 512) {
        int o = p - PADL;
        if (o < 0 || o >= OUT_PER_B) continue;
        int thi = p >> 8;          if (thi > NFRAMES-1) thi = NFRAMES-1;
        int tlo = (p - 768) >> 8;  if (tlo < 0) tlo = 0;
        float sum = 0.f, env = 0.f;
        for (int t = tlo; t <= thi; ++t) {
            int n = p - (t << 8);
            float wv = swin[n];
            sum += lds[(t - t0)*REGION + n];
            env += wv * wv;
        }
        outb[o] = sum / fmaxf(env, 1e-11f);
    }
}

extern "C" void kernel_launch(void* const* d_in, const int* in_sizes, int n_in,
                              void* d_out, int out_size, void* d_ws, size_t ws_size,
                              hipStream_t stream) {
    const float* sr  = (const float*)d_in[0];
    const float* si  = (const float*)d_in[1];
    const float* win = (const float*)d_in[2];
    float* out = (float*)d_out;
    istft_kernel<<<dim3(BATCH*JBLK), dim3(512), 0, stream>>>(sr, si, win, out);
}